// Round 14
// baseline (155.805 us; speedup 1.0000x reference)
//
#include <hip/hip_runtime.h>
#include <hip/hip_bf16.h>
#include <math.h>

#define NB 4
#define NS 1024
#define ND 1024
#define NH 16
#define NDH 64
#define M4 4194304
#define M1 1048576

typedef float f16v __attribute__((ext_vector_type(16)));
typedef short bf8 __attribute__((ext_vector_type(8)));
typedef unsigned short ushort_t;

union U8 { bf8 v; unsigned u[4]; unsigned short s[8]; };

__device__ __forceinline__ unsigned pk(float lo, float hi) {
    __hip_bfloat162 h2 = __float22bfloat162_rn(make_float2(lo, hi));
    return *reinterpret_cast<unsigned*>(&h2);
}
__device__ __forceinline__ unsigned short f2b(float f) {
    unsigned u = __float_as_uint(f);
    unsigned r = (u + 0x7fffu + ((u >> 16) & 1u)) >> 16;   // RNE
    return (unsigned short)r;
}
__device__ __forceinline__ float b2f(unsigned short h) {
    return __uint_as_float(((unsigned)h) << 16);
}
__device__ __forceinline__ f16v zero16() {
    f16v z;
    #pragma unroll
    for (int i = 0; i < 16; ++i) z[i] = 0.f;
    return z;
}
__device__ __forceinline__ void vscale(f16v& v, float s) {
    #pragma unroll
    for (int i = 0; i < 16; ++i) v[i] *= s;
}

// async global->LDS, 16B per lane (wave-uniform base + lane*16 layout)
__device__ __forceinline__ void gl_lds16(const ushort_t* g, ushort_t* l) {
    __builtin_amdgcn_global_load_lds(
        (const __attribute__((address_space(1))) unsigned int*)g,
        (__attribute__((address_space(3))) unsigned int*)l,
        16, 0, 0);
}

// Half-exchange frag builder: result dwords = [h'=0's p_{2h},p_{2h+1}, h'=1's p_{2h},p_{2h+1}]
__device__ __forceinline__ bf8 mkB(unsigned p0, unsigned p1, unsigned p2, unsigned p3, int h) {
    unsigned own0 = h ? p2 : p0;
    unsigned own1 = h ? p3 : p1;
    unsigned ct0  = h ? p0 : p2;
    unsigned ct1  = h ? p1 : p3;
    unsigned x0 = (unsigned)__shfl_xor((int)ct0, 32);
    unsigned x1 = (unsigned)__shfl_xor((int)ct1, 32);
    U8 B;
    B.u[0] = h ? x0 : own0;
    B.u[1] = h ? x1 : own1;
    B.u[2] = h ? own0 : x0;
    B.u[3] = h ? own1 : x1;
    return B.v;
}

// ===========================================================================
// Frag-order layouts (unchanged):
// K planes  [bh][s][c][lane][8]   (kmF,k2F,kvF consecutive, stride M4)
// V planes  [bh][s][dt*2+c2][lane][8] (vmF,wF,vvF consecutive, stride M4)
// x planes  [mt][kc][lane][8]     (fxF,fvxF,fx2F consecutive, stride M4)
// W planes  [nt][kc][lane][8]     (fmF,fw2F,fvF consecutive, stride M1)
// ===========================================================================

// merged prep: blocks [0,2048) do K/V planes; [2048, 4608) do x/W planes.
__global__ __launch_bounds__(256)
void prep_all(const float* __restrict__ x, const float* __restrict__ vx,
              const float* __restrict__ K,  const float* __restrict__ VK,
              const float* __restrict__ Vv, const float* __restrict__ VV,
              const float* __restrict__ Wm, const float* __restrict__ Wv,
              ushort_t* __restrict__ kmF, ushort_t* __restrict__ k2F, ushort_t* __restrict__ kvF,
              ushort_t* __restrict__ vmF, ushort_t* __restrict__ wF,  ushort_t* __restrict__ vvF,
              ushort_t* __restrict__ fx, ushort_t* __restrict__ fvx, ushort_t* __restrict__ fx2,
              ushort_t* __restrict__ fm, ushort_t* __restrict__ fw2, ushort_t* __restrict__ fv)
{
    __shared__ ushort_t Lm[2048], Lw[2048], Lv[2048];
    const int tid = threadIdx.x;
    const int bid = blockIdx.x;

    if (bid < 2048) {
        const int bh = bid >> 5, s = bid & 31;
        const int jp  = tid >> 3;
        const int dh0 = (tid & 7) * 8;
        const size_t gin = ((size_t)bh * NS + s * 32 + jp) * NDH + dh0;
        const size_t sbase = ((size_t)bh * 32 + s) * 2048;

        float kk[8], uu[8], vm[8], vv[8];
        *(float4*)(kk)   = *(const float4*)(K  + gin); *(float4*)(kk+4) = *(const float4*)(K  + gin + 4);
        *(float4*)(uu)   = *(const float4*)(VK + gin); *(float4*)(uu+4) = *(const float4*)(VK + gin + 4);
        *(float4*)(vm)   = *(const float4*)(Vv + gin); *(float4*)(vm+4) = *(const float4*)(Vv + gin + 4);
        *(float4*)(vv)   = *(const float4*)(VV + gin); *(float4*)(vv+4) = *(const float4*)(VV + gin + 4);

        const size_t kout = sbase + (size_t)((tid & 7) >> 1) * 512
                          + (jp + 32 * ((tid & 7) & 1)) * 8;
        unsigned o0[4], o1[4], o2[4];
        #pragma unroll
        for (int t = 0; t < 4; ++t) {
            o0[t] = pk(kk[2*t], kk[2*t+1]);
            o1[t] = pk(fmaf(kk[2*t],kk[2*t],uu[2*t]), fmaf(kk[2*t+1],kk[2*t+1],uu[2*t+1]));
            o2[t] = pk(uu[2*t], uu[2*t+1]);
        }
        *(uint4*)(kmF + kout) = make_uint4(o0[0],o0[1],o0[2],o0[3]);
        *(uint4*)(k2F + kout) = make_uint4(o1[0],o1[1],o1[2],o1[3]);
        *(uint4*)(kvF + kout) = make_uint4(o2[0],o2[1],o2[2],o2[3]);

        #pragma unroll
        for (int e = 0; e < 8; ++e) {
            const int dh = dh0 + e;
            const int idx = ((dh >> 5) * 2 + (jp >> 4)) * 512
                          + ((dh & 31) + 32 * ((jp >> 3) & 1)) * 8 + (jp & 7);
            Lm[idx] = f2b(vm[e]);
            Lw[idx] = f2b(fmaf(vm[e], vm[e], vv[e]));
            Lv[idx] = f2b(vv[e]);
        }
        __syncthreads();
        const size_t vout = sbase + (size_t)tid * 8;
        *(uint4*)(vmF + vout) = *(const uint4*)(Lm + tid * 8);
        *(uint4*)(wF  + vout) = *(const uint4*)(Lw + tid * 8);
        *(uint4*)(vvF + vout) = *(const uint4*)(Lv + tid * 8);
    } else {
        const size_t g = (size_t)(bid - 2048) * 256 + tid;
        if (g < 524288) {
            const size_t g0 = g * 8;
            const int row = (int)(g0 >> 10), k0 = (int)(g0 & 1023);
            const size_t fo = ((size_t)(row >> 5) * 64 + (k0 >> 4)) * 512
                            + ((row & 31) + 32 * ((k0 >> 3) & 1)) * 8;
            float a[8], c[8];
            *(float4*)(a)   = *(const float4*)(x + g0);  *(float4*)(a+4) = *(const float4*)(x + g0 + 4);
            *(float4*)(c)   = *(const float4*)(vx + g0); *(float4*)(c+4) = *(const float4*)(vx + g0 + 4);
            *(uint4*)(fx  + fo) = make_uint4(pk(a[0],a[1]), pk(a[2],a[3]), pk(a[4],a[5]), pk(a[6],a[7]));
            *(uint4*)(fvx + fo) = make_uint4(pk(c[0],c[1]), pk(c[2],c[3]), pk(c[4],c[5]), pk(c[6],c[7]));
            *(uint4*)(fx2 + fo) = make_uint4(pk(a[0]*a[0],a[1]*a[1]), pk(a[2]*a[2],a[3]*a[3]),
                                             pk(a[4]*a[4],a[5]*a[5]), pk(a[6]*a[6],a[7]*a[7]));
        } else {
            const size_t g0 = (g - 524288) * 8;
            const int row = (int)(g0 >> 10), k0 = (int)(g0 & 1023);
            const size_t fo = ((size_t)(row >> 5) * 64 + (k0 >> 4)) * 512
                            + ((row & 31) + 32 * ((k0 >> 3) & 1)) * 8;
            float a[8], c[8];
            *(float4*)(a)   = *(const float4*)(Wm + g0); *(float4*)(a+4) = *(const float4*)(Wm + g0 + 4);
            *(float4*)(c)   = *(const float4*)(Wv + g0); *(float4*)(c+4) = *(const float4*)(Wv + g0 + 4);
            *(uint4*)(fm  + fo) = make_uint4(pk(a[0],a[1]), pk(a[2],a[3]), pk(a[4],a[5]), pk(a[6],a[7]));
            *(uint4*)(fv  + fo) = make_uint4(pk(c[0],c[1]), pk(c[2],c[3]), pk(c[4],c[5]), pk(c[6],c[7]));
            *(uint4*)(fw2 + fo) = make_uint4(pk(fmaf(a[0],a[0],c[0]), fmaf(a[1],a[1],c[1])),
                                             pk(fmaf(a[2],a[2],c[2]), fmaf(a[3],a[3],c[3])),
                                             pk(fmaf(a[4],a[4],c[4]), fmaf(a[5],a[5],c[5])),
                                             pk(fmaf(a[6],a[6],c[6]), fmaf(a[7],a[7],c[7])));
        }
    }
}

// ---------------------------------------------------------------------------
// Fused kernel. Phase A = q-projection, now BARRIER-FREE: all 9 frags/step
// (3 x + 6 W) loaded directly to registers (coalesced frag-order), depth-1
// software pipeline with two named frag sets (static indexing). W is L2-hot
// (384 KB/head-slice, XCD-chunked decode). Phase B = r13 attention skeleton.
// ---------------------------------------------------------------------------
__global__ __launch_bounds__(256, 2)
void attn_fused(const ushort_t* __restrict__ xplanes,  // fxF (3 planes, stride M4)
                const ushort_t* __restrict__ wplanes,  // fmF (3 planes, stride M1)
                const ushort_t* __restrict__ planes,   // kmF (6 planes, stride M4)
                const float* __restrict__ x,
                float* __restrict__ out0, float* __restrict__ out1)
{
    __shared__ union {
        ushort_t stg[3][6 * 2048];   // 72 KiB phase-B K/V staging
        float ep[128][66];           // epilogue scratch
    } sm;

    const int tid  = threadIdx.x;
    const int w    = tid >> 6;
    const int lane = tid & 63;
    const int lh   = lane & 31;
    const int h    = lane >> 5;
    // decode: XCD-chunked; head fastest (16 heads share the x-slice in L2).
    // rb: u bijective in xcd per g; g -> g+2 maps rb -> 7-rb (complement pair).
    const int blk  = blockIdx.x;
    const int lb   = (blk & 7) * 64 + (blk >> 3);
    const int xcd  = lb >> 6;
    const int head = lb & 15;
    const int g    = (lb >> 4) & 3;
    const int b    = g;
    const int u    = (2 * (g & 1) + xcd) & 7;
    const int rb   = (g & 2) ? (7 - u) : u;
    const int bh   = b * 16 + head;
    const int rt   = rb * 4 + w;
    const size_t base = (size_t)bh * 65536;

    // =================== phase A: q projection (registers, no barriers) ======
    const int mt = b * 32 + rb * 4 + w;              // this wave's 32-row x tile

    f16v aQ0 = zero16(), aQ1 = zero16(), aV0 = zero16(), aV1 = zero16();

    const ushort_t* xb    = xplanes + (size_t)mt * 64 * 512 + lane * 8;
    const ushort_t* wsrc0 = wplanes + (size_t)(head * 2) * 64 * 512 + lane * 8;
    // nt1 base = wsrc0 + 64*512 = +32768

#define LOADF(dst, ks) do {                                                  \
    dst[0] = *(const bf8*)(xb    + 0 * (size_t)M4 + (ks) * 512);             \
    dst[1] = *(const bf8*)(xb    + 1 * (size_t)M4 + (ks) * 512);             \
    dst[2] = *(const bf8*)(xb    + 2 * (size_t)M4 + (ks) * 512);             \
    dst[3] = *(const bf8*)(wsrc0 + 0 * (size_t)M1 + (ks) * 512);             \
    dst[4] = *(const bf8*)(wsrc0 + 1 * (size_t)M1 + (ks) * 512);             \
    dst[5] = *(const bf8*)(wsrc0 + 2 * (size_t)M1 + (ks) * 512);             \
    dst[6] = *(const bf8*)(wsrc0 + 32768 + 0 * (size_t)M1 + (ks) * 512);     \
    dst[7] = *(const bf8*)(wsrc0 + 32768 + 1 * (size_t)M1 + (ks) * 512);     \
    dst[8] = *(const bf8*)(wsrc0 + 32768 + 2 * (size_t)M1 + (ks) * 512);     \
} while (0)

#define MFMA6(f) do {                                                        \
    aQ0 = __builtin_amdgcn_mfma_f32_32x32x16_bf16(f[3], f[0], aQ0, 0, 0, 0); \
    aV0 = __builtin_amdgcn_mfma_f32_32x32x16_bf16(f[4], f[1], aV0, 0, 0, 0); \
    aV0 = __builtin_amdgcn_mfma_f32_32x32x16_bf16(f[5], f[2], aV0, 0, 0, 0); \
    aQ1 = __builtin_amdgcn_mfma_f32_32x32x16_bf16(f[6], f[0], aQ1, 0, 0, 0); \
    aV1 = __builtin_amdgcn_mfma_f32_32x32x16_bf16(f[7], f[1], aV1, 0, 0, 0); \
    aV1 = __builtin_amdgcn_mfma_f32_32x32x16_bf16(f[8], f[2], aV1, 0, 0, 0); \
} while (0)

    {
        bf8 fA[9], fB[9];
        LOADF(fA, 0);
        for (int ks = 0; ks < 64; ks += 2) {
            LOADF(fB, ks + 1);
            MFMA6(fA);
            if (ks + 2 < 64) LOADF(fA, ks + 2);
            MFMA6(fB);
        }
    }
#undef LOADF
#undef MFMA6

    // Build attn Q-frags in registers (layout algebra verified r12).
    bf8 fqm[4], fvq[4], fq2[4];
    {
        const float S1 = 0.03125f, S2 = 0.0009765625f;
        unsigned Uq[16], Uv[16];
        #pragma unroll
        for (int k = 0; k < 8; ++k) {
            Uq[k]     = pk(aQ0[2*k] * S1, aQ0[2*k+1] * S1);
            Uq[8 + k] = pk(aQ1[2*k] * S1, aQ1[2*k+1] * S1);
            Uv[k]     = pk(aV0[2*k] * S2, aV0[2*k+1] * S2);
            Uv[8 + k] = pk(aV1[2*k] * S2, aV1[2*k+1] * S2);
        }
        #pragma unroll
        for (int c = 0; c < 4; ++c) {
            fqm[c] = mkB(Uq[4*c], Uq[4*c+1], Uq[4*c+2], Uq[4*c+3], h);
            fvq[c] = mkB(Uv[4*c], Uv[4*c+1], Uv[4*c+2], Uv[4*c+3], h);
            U8 t; t.v = fqm[c];
            U8 r;
            #pragma unroll
            for (int k = 0; k < 4; ++k) {
                float q0 = b2f(t.s[2*k]), q1 = b2f(t.s[2*k+1]);
                r.u[k] = pk(q0*q0, q1*q1);
            }
            fq2[c] = r.v;
        }
    }

    // phase boundary: drain own vmem (phase-B vmcnt counting) + converge.
    asm volatile("s_waitcnt vmcnt(0) lgkmcnt(0)" ::: "memory");
    __builtin_amdgcn_s_barrier();

    // =================== phase B: attention (r13 skeleton) ===================
    f16v aN1[2], aN2w[2], aM2[2], aN3[2];
    #pragma unroll
    for (int dt = 0; dt < 2; ++dt) { aN1[dt]=zero16(); aN2w[dt]=zero16(); aM2[dt]=zero16(); aN3[dt]=zero16(); }
    float mrun = -INFINITY, Zrun = 0.f, S2run = 0.f;

    const int nstage = 4 * rb + 4;
    #pragma unroll
    for (int p = 0; p < 6; ++p)
        gl_lds16(planes + (size_t)p * M4 + base + w * 512 + lane * 8,
                 &sm.stg[0][p * 2048 + w * 512 + lane * 8]);
    #pragma unroll
    for (int p = 0; p < 6; ++p)
        gl_lds16(planes + (size_t)p * M4 + base + 2048 + w * 512 + lane * 8,
                 &sm.stg[1][p * 2048 + w * 512 + lane * 8]);

    for (int st = 0; st < nstage; ++st) {
        const int cur = st % 3;
        if (st + 2 < nstage) {
            const int nxt = (st + 2) % 3;
            #pragma unroll
            for (int p = 0; p < 6; ++p)
                gl_lds16(planes + (size_t)p * M4 + base + (size_t)(st + 2) * 2048 + w * 512 + lane * 8,
                         &sm.stg[nxt][p * 2048 + w * 512 + lane * 8]);
            asm volatile("s_waitcnt vmcnt(12)" ::: "memory");
        } else if (st + 1 < nstage) {
            asm volatile("s_waitcnt vmcnt(6)" ::: "memory");
        } else {
            asm volatile("s_waitcnt vmcnt(0)" ::: "memory");
        }
        __builtin_amdgcn_s_barrier();
        __builtin_amdgcn_sched_barrier(0);

        if (st <= rt) {
            __builtin_amdgcn_s_setprio(1);
            const ushort_t* sb = sm.stg[cur];
            // ---- phase 1: scores ----
            f16v accA = zero16(), accU = zero16();
            #pragma unroll
            for (int c = 0; c < 4; ++c) {
                bf8 A0 = *(const bf8*)(sb + 0 * 2048 + c * 512 + lane * 8);
                bf8 A1 = *(const bf8*)(sb + 1 * 2048 + c * 512 + lane * 8);
                bf8 A2 = *(const bf8*)(sb + 2 * 2048 + c * 512 + lane * 8);
                accA = __builtin_amdgcn_mfma_f32_32x32x16_bf16(A0, fqm[c], accA, 0, 0, 0);
                accU = __builtin_amdgcn_mfma_f32_32x32x16_bf16(A1, fvq[c], accU, 0, 0, 0);
                accU = __builtin_amdgcn_mfma_f32_32x32x16_bf16(A2, fq2[c], accU, 0, 0, 0);
            }
            if (st == rt) {                   // diagonal: mask j_loc > lh
                #pragma unroll
                for (int i = 0; i < 16; ++i) {
                    const int jl = (i & 3) + 8 * (i >> 2) + 4 * h;
                    if (jl > lh) accA[i] = -INFINITY;
                }
            }
            // ---- online softmax with defer-max (tree reductions) ----
            float t8[8];
            #pragma unroll
            for (int i = 0; i < 8; ++i) t8[i] = fmaxf(accA[i], accA[i + 8]);
            #pragma unroll
            for (int i = 0; i < 4; ++i) t8[i] = fmaxf(t8[i], t8[i + 4]);
            float mx = fmaxf(fmaxf(t8[0], t8[1]), fmaxf(t8[2], t8[3]));
            mx = fmaxf(mx, __shfl_xor(mx, 32));
            if (!__all(mx <= mrun + 8.f)) {
                const float mnew = fmaxf(mrun, mx);
                const float s1 = __expf(mrun - mnew);
                const float s2 = s1 * s1, s3 = s2 * s1;
                Zrun *= s1; S2run *= s2;
                #pragma unroll
                for (int dt = 0; dt < 2; ++dt) { vscale(aN1[dt],s1); vscale(aN2w[dt],s2); vscale(aM2[dt],s2); vscale(aN3[dt],s3); }
                mrun = mnew;
            }
            float zt[8], sq[8];
            #pragma unroll
            for (int i = 0; i < 16; ++i) accA[i] = __expf(accA[i] - mrun);
            #pragma unroll
            for (int i = 0; i < 8; ++i) {
                zt[i] = accA[i] + accA[i + 8];
                sq[i] = fmaf(accA[i] * accA[i], accU[i],
                             accA[i + 8] * accA[i + 8] * accU[i + 8]);
            }
            #pragma unroll
            for (int i = 0; i < 4; ++i) { zt[i] += zt[i + 4]; sq[i] += sq[i + 4]; }
            float Zt = (zt[0] + zt[1]) + (zt[2] + zt[3]);
            float St = (sq[0] + sq[1]) + (sq[2] + sq[3]);
            Zt += __shfl_xor(Zt, 32); St += __shfl_xor(St, 32);
            Zrun += Zt; S2run += St;

            // ---- phase 2: PV ----
            #pragma unroll
            for (int c2 = 0; c2 < 2; ++c2) {
                unsigned pE[4], pE2[4], pEU[4], pE3[4];
                #pragma unroll
                for (int k = 0; k < 4; ++k) {
                    const int i0 = 8*c2 + 2*k;
                    const float e0 = accA[i0], e1 = accA[i0+1];
                    const float q0 = e0*e0, q1 = e1*e1;
                    const float t0 = q0*accU[i0], t1 = q1*accU[i0+1];
                    pE [k] = pk(e0, e1);
                    pE2[k] = pk(q0, q1);
                    pEU[k] = pk(t0, t1);
                    pE3[k] = pk(t0*e0, t1*e1);
                }
                bf8 BE  = mkB(pE [0], pE [1], pE [2], pE [3], h);
                bf8 BE2 = mkB(pE2[0], pE2[1], pE2[2], pE2[3], h);
                bf8 BEU = mkB(pEU[0], pEU[1], pEU[2], pEU[3], h);
                bf8 BE3 = mkB(pE3[0], pE3[1], pE3[2], pE3[3], h);
                #pragma unroll
                for (int dt = 0; dt < 2; ++dt) {
                    const ushort_t* vp = sb + 3 * 2048 + (dt * 2 + c2) * 512 + lane * 8;
                    bf8 Am = *(const bf8*)(vp + 0 * 2048);
                    bf8 Aw = *(const bf8*)(vp + 1 * 2048);
                    bf8 Av = *(const bf8*)(vp + 2 * 2048);
                    aN1[dt]  = __builtin_amdgcn_mfma_f32_32x32x16_bf16(Am, BE,  aN1[dt],  0, 0, 0);
                    aN2w[dt] = __builtin_amdgcn_mfma_f32_32x32x16_bf16(Aw, BE2, aN2w[dt], 0, 0, 0);
                    aM2[dt]  = __builtin_amdgcn_mfma_f32_32x32x16_bf16(Aw, BEU, aM2[dt],  0, 0, 0);
                    aM2[dt]  = __builtin_amdgcn_mfma_f32_32x32x16_bf16(Av, BE2, aM2[dt],  0, 0, 0);
                    aN3[dt]  = __builtin_amdgcn_mfma_f32_32x32x16_bf16(Aw, BE3, aN3[dt],  0, 0, 0);
                }
            }
            __builtin_amdgcn_s_setprio(0);
        }
        __builtin_amdgcn_sched_barrier(0);
        __builtin_amdgcn_s_barrier();
    }

    // ---- epilogue ----
    const float rZ  = 1.f / Zrun;
    const float rZ2 = rZ * rZ;
    const float sS  = S2run * rZ2;

    #pragma unroll
    for (int dt = 0; dt < 2; ++dt)
        #pragma unroll
        for (int i = 0; i < 16; ++i) {
            const int col = 32*dt + (i & 3) + 8*(i >> 2) + 4*h;
            sm.ep[w*32 + lh][col] = aN1[dt][i] * rZ;
        }
    __syncthreads();
    {
        const int row = tid >> 1, half = (tid & 1) * 32;
        const size_t o = ((size_t)b * NS + rb*128 + row) * ND + head * NDH + half;
        #pragma unroll
        for (int q4 = 0; q4 < 32; q4 += 4) {
            float4 t = make_float4(sm.ep[row][half+q4], sm.ep[row][half+q4+1],
                                   sm.ep[row][half+q4+2], sm.ep[row][half+q4+3]);
            float4 xi = *(const float4*)(x + o + q4);
            *(float4*)(out0 + o + q4) = make_float4(t.x+xi.x, t.y+xi.y, t.z+xi.z, t.w+xi.w);
        }
    }
    __syncthreads();
    #pragma unroll
    for (int dt = 0; dt < 2; ++dt)
        #pragma unroll
        for (int i = 0; i < 16; ++i) {
            const int col = 32*dt + (i & 3) + 8*(i >> 2) + 4*h;
            sm.ep[w*32 + lh][col] = rZ2 * fmaf(sS, aN2w[dt][i], aM2[dt][i]) - 2.f*rZ2*rZ*aN3[dt][i];
        }
    __syncthreads();
    {
        const int row = tid >> 1, half = (tid & 1) * 32;
        const size_t o = ((size_t)b * NS + rb*128 + row) * ND + head * NDH + half;
        #pragma unroll
        for (int q4 = 0; q4 < 32; q4 += 4) {
            float4 t = make_float4(sm.ep[row][half+q4], sm.ep[row][half+q4+1],
                                   sm.ep[row][half+q4+2], sm.ep[row][half+q4+3]);
            *(float4*)(out1 + o + q4) = t;
        }
    }
}

extern "C" void kernel_launch(void* const* d_in, const int* in_sizes, int n_in,
                              void* d_out, int out_size, void* d_ws, size_t ws_size,
                              hipStream_t stream)
{
    (void)in_sizes; (void)n_in; (void)out_size; (void)ws_size;
    const float* x  = (const float*)d_in[0];
    const float* vx = (const float*)d_in[1];
    const float* K  = (const float*)d_in[2];
    const float* VK = (const float*)d_in[3];
    const float* Vv = (const float*)d_in[4];
    const float* VV = (const float*)d_in[5];
    const float* Wm = (const float*)d_in[6];
    const float* Wv = (const float*)d_in[7];

    float* out0 = (float*)d_out;
    float* out1 = out0 + (size_t)NB * NS * ND;

    ushort_t* kmF = (ushort_t*)d_ws;   // 6 consecutive planes: kmF,k2F,kvF,vmF,wF,vvF
    ushort_t* k2F = kmF + M4;
    ushort_t* kvF = k2F + M4;
    ushort_t* vmF = kvF + M4;
    ushort_t* wF  = vmF + M4;
    ushort_t* vvF = wF  + M4;
    ushort_t* fxF = vvF + M4;          // 3 consecutive planes: fxF,fvxF,fx2F
    ushort_t* fvxF= fxF + M4;
    ushort_t* fx2F= fvxF+ M4;
    ushort_t* fmF = fx2F+ M4;          // 3 consecutive planes: fmF,fw2F,fvF
    ushort_t* fw2F= fmF + M1;
    ushort_t* fvF = fw2F+ M1;

    prep_all<<<4608, 256, 0, stream>>>(x, vx, K, VK, Vv, VV, Wm, Wv,
                                       kmF, k2F, kvF, vmF, wF, vvF,
                                       fxF, fvxF, fx2F, fmF, fw2F, fvF);
    attn_fused<<<512, 256, 0, stream>>>(fxF, fmF, kmF, x, out0, out1);
}

// Round 15
// 146.915 us; speedup vs baseline: 1.0605x; 1.0605x over previous
//
#include <hip/hip_runtime.h>
#include <hip/hip_bf16.h>
#include <math.h>

#define NB 4
#define NS 1024
#define ND 1024
#define NH 16
#define NDH 64
#define M4 4194304
#define M1 1048576

typedef float f16v __attribute__((ext_vector_type(16)));
typedef short bf8 __attribute__((ext_vector_type(8)));
typedef unsigned short ushort_t;

union U8 { bf8 v; unsigned u[4]; unsigned short s[8]; };

__device__ __forceinline__ unsigned pk(float lo, float hi) {
    __hip_bfloat162 h2 = __float22bfloat162_rn(make_float2(lo, hi));
    return *reinterpret_cast<unsigned*>(&h2);
}
__device__ __forceinline__ unsigned short f2b(float f) {
    unsigned u = __float_as_uint(f);
    unsigned r = (u + 0x7fffu + ((u >> 16) & 1u)) >> 16;   // RNE
    return (unsigned short)r;
}
__device__ __forceinline__ float b2f(unsigned short h) {
    return __uint_as_float(((unsigned)h) << 16);
}
__device__ __forceinline__ f16v zero16() {
    f16v z;
    #pragma unroll
    for (int i = 0; i < 16; ++i) z[i] = 0.f;
    return z;
}
__device__ __forceinline__ void vscale(f16v& v, float s) {
    #pragma unroll
    for (int i = 0; i < 16; ++i) v[i] *= s;
}

// async global->LDS, 16B per lane (wave-uniform base + lane*16 layout)
__device__ __forceinline__ void gl_lds16(const ushort_t* g, ushort_t* l) {
    __builtin_amdgcn_global_load_lds(
        (const __attribute__((address_space(1))) unsigned int*)g,
        (__attribute__((address_space(3))) unsigned int*)l,
        16, 0, 0);
}

// Half-exchange frag builder: result dwords = [h'=0's p_{2h},p_{2h+1}, h'=1's p_{2h},p_{2h+1}]
__device__ __forceinline__ bf8 mkB(unsigned p0, unsigned p1, unsigned p2, unsigned p3, int h) {
    unsigned own0 = h ? p2 : p0;
    unsigned own1 = h ? p3 : p1;
    unsigned ct0  = h ? p0 : p2;
    unsigned ct1  = h ? p1 : p3;
    unsigned x0 = (unsigned)__shfl_xor((int)ct0, 32);
    unsigned x1 = (unsigned)__shfl_xor((int)ct1, 32);
    U8 B;
    B.u[0] = h ? x0 : own0;
    B.u[1] = h ? x1 : own1;
    B.u[2] = h ? own0 : x0;
    B.u[3] = h ? own1 : x1;
    return B.v;
}

// ===========================================================================
// Frag-order layouts (unchanged):
// K planes  [bh][s][c][lane][8]   (kmF,k2F,kvF consecutive, stride M4)
// V planes  [bh][s][dt*2+c2][lane][8] (vmF,wF,vvF consecutive, stride M4)
// x planes  [mt][kc][lane][8]     (fxF,fvxF,fx2F consecutive, stride M4)
// W planes  [nt][kc][lane][8]     (fmF,fw2F,fvF consecutive, stride M1)
// ===========================================================================

// merged prep: blocks [0,2048) do K/V planes; [2048, 4608) do x/W planes.
__global__ __launch_bounds__(256)
void prep_all(const float* __restrict__ x, const float* __restrict__ vx,
              const float* __restrict__ K,  const float* __restrict__ VK,
              const float* __restrict__ Vv, const float* __restrict__ VV,
              const float* __restrict__ Wm, const float* __restrict__ Wv,
              ushort_t* __restrict__ kmF, ushort_t* __restrict__ k2F, ushort_t* __restrict__ kvF,
              ushort_t* __restrict__ vmF, ushort_t* __restrict__ wF,  ushort_t* __restrict__ vvF,
              ushort_t* __restrict__ fx, ushort_t* __restrict__ fvx, ushort_t* __restrict__ fx2,
              ushort_t* __restrict__ fm, ushort_t* __restrict__ fw2, ushort_t* __restrict__ fv)
{
    __shared__ ushort_t Lm[2048], Lw[2048], Lv[2048];
    const int tid = threadIdx.x;
    const int bid = blockIdx.x;

    if (bid < 2048) {
        const int bh = bid >> 5, s = bid & 31;
        const int jp  = tid >> 3;
        const int dh0 = (tid & 7) * 8;
        const size_t gin = ((size_t)bh * NS + s * 32 + jp) * NDH + dh0;
        const size_t sbase = ((size_t)bh * 32 + s) * 2048;

        float kk[8], uu[8], vm[8], vv[8];
        *(float4*)(kk)   = *(const float4*)(K  + gin); *(float4*)(kk+4) = *(const float4*)(K  + gin + 4);
        *(float4*)(uu)   = *(const float4*)(VK + gin); *(float4*)(uu+4) = *(const float4*)(VK + gin + 4);
        *(float4*)(vm)   = *(const float4*)(Vv + gin); *(float4*)(vm+4) = *(const float4*)(Vv + gin + 4);
        *(float4*)(vv)   = *(const float4*)(VV + gin); *(float4*)(vv+4) = *(const float4*)(VV + gin + 4);

        const size_t kout = sbase + (size_t)((tid & 7) >> 1) * 512
                          + (jp + 32 * ((tid & 7) & 1)) * 8;
        unsigned o0[4], o1[4], o2[4];
        #pragma unroll
        for (int t = 0; t < 4; ++t) {
            o0[t] = pk(kk[2*t], kk[2*t+1]);
            o1[t] = pk(fmaf(kk[2*t],kk[2*t],uu[2*t]), fmaf(kk[2*t+1],kk[2*t+1],uu[2*t+1]));
            o2[t] = pk(uu[2*t], uu[2*t+1]);
        }
        *(uint4*)(kmF + kout) = make_uint4(o0[0],o0[1],o0[2],o0[3]);
        *(uint4*)(k2F + kout) = make_uint4(o1[0],o1[1],o1[2],o1[3]);
        *(uint4*)(kvF + kout) = make_uint4(o2[0],o2[1],o2[2],o2[3]);

        #pragma unroll
        for (int e = 0; e < 8; ++e) {
            const int dh = dh0 + e;
            const int idx = ((dh >> 5) * 2 + (jp >> 4)) * 512
                          + ((dh & 31) + 32 * ((jp >> 3) & 1)) * 8 + (jp & 7);
            Lm[idx] = f2b(vm[e]);
            Lw[idx] = f2b(fmaf(vm[e], vm[e], vv[e]));
            Lv[idx] = f2b(vv[e]);
        }
        __syncthreads();
        const size_t vout = sbase + (size_t)tid * 8;
        *(uint4*)(vmF + vout) = *(const uint4*)(Lm + tid * 8);
        *(uint4*)(wF  + vout) = *(const uint4*)(Lw + tid * 8);
        *(uint4*)(vvF + vout) = *(const uint4*)(Lv + tid * 8);
    } else {
        const size_t g = (size_t)(bid - 2048) * 256 + tid;
        if (g < 524288) {
            const size_t g0 = g * 8;
            const int row = (int)(g0 >> 10), k0 = (int)(g0 & 1023);
            const size_t fo = ((size_t)(row >> 5) * 64 + (k0 >> 4)) * 512
                            + ((row & 31) + 32 * ((k0 >> 3) & 1)) * 8;
            float a[8], c[8];
            *(float4*)(a)   = *(const float4*)(x + g0);  *(float4*)(a+4) = *(const float4*)(x + g0 + 4);
            *(float4*)(c)   = *(const float4*)(vx + g0); *(float4*)(c+4) = *(const float4*)(vx + g0 + 4);
            *(uint4*)(fx  + fo) = make_uint4(pk(a[0],a[1]), pk(a[2],a[3]), pk(a[4],a[5]), pk(a[6],a[7]));
            *(uint4*)(fvx + fo) = make_uint4(pk(c[0],c[1]), pk(c[2],c[3]), pk(c[4],c[5]), pk(c[6],c[7]));
            *(uint4*)(fx2 + fo) = make_uint4(pk(a[0]*a[0],a[1]*a[1]), pk(a[2]*a[2],a[3]*a[3]),
                                             pk(a[4]*a[4],a[5]*a[5]), pk(a[6]*a[6],a[7]*a[7]));
        } else {
            const size_t g0 = (g - 524288) * 8;
            const int row = (int)(g0 >> 10), k0 = (int)(g0 & 1023);
            const size_t fo = ((size_t)(row >> 5) * 64 + (k0 >> 4)) * 512
                            + ((row & 31) + 32 * ((k0 >> 3) & 1)) * 8;
            float a[8], c[8];
            *(float4*)(a)   = *(const float4*)(Wm + g0); *(float4*)(a+4) = *(const float4*)(Wm + g0 + 4);
            *(float4*)(c)   = *(const float4*)(Wv + g0); *(float4*)(c+4) = *(const float4*)(Wv + g0 + 4);
            *(uint4*)(fm  + fo) = make_uint4(pk(a[0],a[1]), pk(a[2],a[3]), pk(a[4],a[5]), pk(a[6],a[7]));
            *(uint4*)(fv  + fo) = make_uint4(pk(c[0],c[1]), pk(c[2],c[3]), pk(c[4],c[5]), pk(c[6],c[7]));
            *(uint4*)(fw2 + fo) = make_uint4(pk(fmaf(a[0],a[0],c[0]), fmaf(a[1],a[1],c[1])),
                                             pk(fmaf(a[2],a[2],c[2]), fmaf(a[3],a[3],c[3])),
                                             pk(fmaf(a[4],a[4],c[4]), fmaf(a[5],a[5],c[5])),
                                             pk(fmaf(a[6],a[6],c[6]), fmaf(a[7],a[7],c[7])));
        }
    }
}

// ---------------------------------------------------------------------------
// Fused kernel (r13, best measured): phase A = q-projection with LDS-shared
// W staging (Q stays in registers); phase B = r8-skeleton causal VDP
// attention. Complementary rb pairing balances CU load.
// ---------------------------------------------------------------------------
__global__ __launch_bounds__(256, 2)
void attn_fused(const ushort_t* __restrict__ xplanes,  // fxF (3 planes, stride M4)
                const ushort_t* __restrict__ wplanes,  // fmF (3 planes, stride M1)
                const ushort_t* __restrict__ planes,   // kmF (6 planes, stride M4)
                const float* __restrict__ x,
                float* __restrict__ out0, float* __restrict__ out1)
{
    __shared__ union {
        ushort_t wstg[3][12 * 512];  // 36 KiB phase-A W staging
        ushort_t stg[3][6 * 2048];   // 72 KiB phase-B K/V staging
        float ep[128][66];           // epilogue scratch
    } sm;

    const int tid  = threadIdx.x;
    const int w    = tid >> 6;
    const int lane = tid & 63;
    const int lh   = lane & 31;
    const int h    = lane >> 5;
    // decode: XCD-chunked; head fastest (16 heads share the x-slice in L2).
    // rb: u bijective in xcd per g; g -> g+2 maps rb -> 7-rb (complement pair).
    const int blk  = blockIdx.x;
    const int lb   = (blk & 7) * 64 + (blk >> 3);
    const int xcd  = lb >> 6;
    const int head = lb & 15;
    const int g    = (lb >> 4) & 3;
    const int b    = g;
    const int u    = (2 * (g & 1) + xcd) & 7;
    const int rb   = (g & 2) ? (7 - u) : u;
    const int bh   = b * 16 + head;
    const int rt   = rb * 4 + w;
    const size_t base = (size_t)bh * 65536;

    // =================== phase A: q projection (registers) ===================
    const int mt = b * 32 + rb * 4 + w;              // this wave's 32-row x tile
    const int nt = head * 2 + (w & 1);               // staging assignment

    f16v aQ0 = zero16(), aQ1 = zero16(), aV0 = zero16(), aV1 = zero16();

    const ushort_t* xb = xplanes + (size_t)mt * 64 * 512 + lane * 8;
    const ushort_t* wsrc = wplanes + ((size_t)nt * 64 + (w >> 1)) * 512 + lane * 8;

    #pragma unroll
    for (int q = 0; q < 3; ++q)
        gl_lds16(wsrc + (size_t)q * M1, &sm.wstg[0][(3 * w + q) * 512 + lane * 8]);
    #pragma unroll
    for (int q = 0; q < 3; ++q)
        gl_lds16(wsrc + (size_t)q * M1 + 2 * 512, &sm.wstg[1][(3 * w + q) * 512 + lane * 8]);

    bf8 xc[6], xn[6];
    #pragma unroll
    for (int kcL = 0; kcL < 2; ++kcL)
        #pragma unroll
        for (int q = 0; q < 3; ++q)
            xc[3 * kcL + q] = *(const bf8*)(xb + (size_t)q * M4 + kcL * 512);

    for (int t = 0; t < 32; ++t) {
        const int cur = t % 3;
        if (t < 31) asm volatile("s_waitcnt vmcnt(9)" ::: "memory");
        else        asm volatile("s_waitcnt vmcnt(6)" ::: "memory");
        __builtin_amdgcn_s_barrier();
        if (t + 2 < 32) {
            const int nxt = (t + 2) % 3;
            #pragma unroll
            for (int q = 0; q < 3; ++q)
                gl_lds16(wsrc + (size_t)q * M1 + (size_t)(2 * (t + 2)) * 512,
                         &sm.wstg[nxt][(3 * w + q) * 512 + lane * 8]);
        }
        __builtin_amdgcn_sched_barrier(0);
        if (t + 1 < 32) {
            #pragma unroll
            for (int kcL = 0; kcL < 2; ++kcL)
                #pragma unroll
                for (int q = 0; q < 3; ++q)
                    xn[3 * kcL + q] = *(const bf8*)(xb + (size_t)q * M4 + (2 * (t + 1) + kcL) * 512);
        }
        const ushort_t* sc = sm.wstg[cur];
        __builtin_amdgcn_s_setprio(1);
        #pragma unroll
        for (int kcL = 0; kcL < 2; ++kcL) {
            bf8 bx  = xc[3 * kcL + 0];
            bf8 bvx = xc[3 * kcL + 1];
            bf8 bx2 = xc[3 * kcL + 2];
            bf8 A0m = *(const bf8*)(sc + (3 * (2 * kcL + 0) + 0) * 512 + lane * 8);
            bf8 A0w = *(const bf8*)(sc + (3 * (2 * kcL + 0) + 1) * 512 + lane * 8);
            bf8 A0v = *(const bf8*)(sc + (3 * (2 * kcL + 0) + 2) * 512 + lane * 8);
            bf8 A1m = *(const bf8*)(sc + (3 * (2 * kcL + 1) + 0) * 512 + lane * 8);
            bf8 A1w = *(const bf8*)(sc + (3 * (2 * kcL + 1) + 1) * 512 + lane * 8);
            bf8 A1v = *(const bf8*)(sc + (3 * (2 * kcL + 1) + 2) * 512 + lane * 8);
            aQ0 = __builtin_amdgcn_mfma_f32_32x32x16_bf16(A0m, bx,  aQ0, 0, 0, 0);
            aV0 = __builtin_amdgcn_mfma_f32_32x32x16_bf16(A0w, bvx, aV0, 0, 0, 0);
            aV0 = __builtin_amdgcn_mfma_f32_32x32x16_bf16(A0v, bx2, aV0, 0, 0, 0);
            aQ1 = __builtin_amdgcn_mfma_f32_32x32x16_bf16(A1m, bx,  aQ1, 0, 0, 0);
            aV1 = __builtin_amdgcn_mfma_f32_32x32x16_bf16(A1w, bvx, aV1, 0, 0, 0);
            aV1 = __builtin_amdgcn_mfma_f32_32x32x16_bf16(A1v, bx2, aV1, 0, 0, 0);
        }
        __builtin_amdgcn_s_setprio(0);
        asm volatile("s_waitcnt lgkmcnt(0)" ::: "memory");
        __builtin_amdgcn_sched_barrier(0);
        #pragma unroll
        for (int q = 0; q < 6; ++q) xc[q] = xn[q];
    }

    // Build attn Q-frags in registers (layout algebra verified r12).
    bf8 fqm[4], fvq[4], fq2[4];
    {
        const float S1 = 0.03125f, S2 = 0.0009765625f;
        unsigned Uq[16], Uv[16];
        #pragma unroll
        for (int k = 0; k < 8; ++k) {
            Uq[k]     = pk(aQ0[2*k] * S1, aQ0[2*k+1] * S1);
            Uq[8 + k] = pk(aQ1[2*k] * S1, aQ1[2*k+1] * S1);
            Uv[k]     = pk(aV0[2*k] * S2, aV0[2*k+1] * S2);
            Uv[8 + k] = pk(aV1[2*k] * S2, aV1[2*k+1] * S2);
        }
        #pragma unroll
        for (int c = 0; c < 4; ++c) {
            fqm[c] = mkB(Uq[4*c], Uq[4*c+1], Uq[4*c+2], Uq[4*c+3], h);
            fvq[c] = mkB(Uv[4*c], Uv[4*c+1], Uv[4*c+2], Uv[4*c+3], h);
            U8 t; t.v = fqm[c];
            U8 r;
            #pragma unroll
            for (int k = 0; k < 4; ++k) {
                float q0 = b2f(t.s[2*k]), q1 = b2f(t.s[2*k+1]);
                r.u[k] = pk(q0*q0, q1*q1);
            }
            fq2[c] = r.v;
        }
    }

    // phase boundary: drain everything, then barrier before LDS reuse.
    asm volatile("s_waitcnt vmcnt(0) lgkmcnt(0)" ::: "memory");
    __builtin_amdgcn_s_barrier();

    // =================== phase B: attention (r8 skeleton) ===================
    f16v aN1[2], aN2w[2], aM2[2], aN3[2];
    #pragma unroll
    for (int dt = 0; dt < 2; ++dt) { aN1[dt]=zero16(); aN2w[dt]=zero16(); aM2[dt]=zero16(); aN3[dt]=zero16(); }
    float mrun = -INFINITY, Zrun = 0.f, S2run = 0.f;

    const int nstage = 4 * rb + 4;
    #pragma unroll
    for (int p = 0; p < 6; ++p)
        gl_lds16(planes + (size_t)p * M4 + base + w * 512 + lane * 8,
                 &sm.stg[0][p * 2048 + w * 512 + lane * 8]);
    #pragma unroll
    for (int p = 0; p < 6; ++p)
        gl_lds16(planes + (size_t)p * M4 + base + 2048 + w * 512 + lane * 8,
                 &sm.stg[1][p * 2048 + w * 512 + lane * 8]);

    for (int st = 0; st < nstage; ++st) {
        const int cur = st % 3;
        if (st + 2 < nstage) {
            const int nxt = (st + 2) % 3;
            #pragma unroll
            for (int p = 0; p < 6; ++p)
                gl_lds16(planes + (size_t)p * M4 + base + (size_t)(st + 2) * 2048 + w * 512 + lane * 8,
                         &sm.stg[nxt][p * 2048 + w * 512 + lane * 8]);
            asm volatile("s_waitcnt vmcnt(12)" ::: "memory");
        } else if (st + 1 < nstage) {
            asm volatile("s_waitcnt vmcnt(6)" ::: "memory");
        } else {
            asm volatile("s_waitcnt vmcnt(0)" ::: "memory");
        }
        __builtin_amdgcn_s_barrier();
        __builtin_amdgcn_sched_barrier(0);

        if (st <= rt) {
            __builtin_amdgcn_s_setprio(1);
            const ushort_t* sb = sm.stg[cur];
            // ---- phase 1: scores ----
            f16v accA = zero16(), accU = zero16();
            #pragma unroll
            for (int c = 0; c < 4; ++c) {
                bf8 A0 = *(const bf8*)(sb + 0 * 2048 + c * 512 + lane * 8);
                bf8 A1 = *(const bf8*)(sb + 1 * 2048 + c * 512 + lane * 8);
                bf8 A2 = *(const bf8*)(sb + 2 * 2048 + c * 512 + lane * 8);
                accA = __builtin_amdgcn_mfma_f32_32x32x16_bf16(A0, fqm[c], accA, 0, 0, 0);
                accU = __builtin_amdgcn_mfma_f32_32x32x16_bf16(A1, fvq[c], accU, 0, 0, 0);
                accU = __builtin_amdgcn_mfma_f32_32x32x16_bf16(A2, fq2[c], accU, 0, 0, 0);
            }
            if (st == rt) {                   // diagonal: mask j_loc > lh
                #pragma unroll
                for (int i = 0; i < 16; ++i) {
                    const int jl = (i & 3) + 8 * (i >> 2) + 4 * h;
                    if (jl > lh) accA[i] = -INFINITY;
                }
            }
            // ---- online softmax with defer-max (tree reductions) ----
            float t8[8];
            #pragma unroll
            for (int i = 0; i < 8; ++i) t8[i] = fmaxf(accA[i], accA[i + 8]);
            #pragma unroll
            for (int i = 0; i < 4; ++i) t8[i] = fmaxf(t8[i], t8[i + 4]);
            float mx = fmaxf(fmaxf(t8[0], t8[1]), fmaxf(t8[2], t8[3]));
            mx = fmaxf(mx, __shfl_xor(mx, 32));
            if (!__all(mx <= mrun + 8.f)) {
                const float mnew = fmaxf(mrun, mx);
                const float s1 = __expf(mrun - mnew);
                const float s2 = s1 * s1, s3 = s2 * s1;
                Zrun *= s1; S2run *= s2;
                #pragma unroll
                for (int dt = 0; dt < 2; ++dt) { vscale(aN1[dt],s1); vscale(aN2w[dt],s2); vscale(aM2[dt],s2); vscale(aN3[dt],s3); }
                mrun = mnew;
            }
            float zt[8], sq[8];
            #pragma unroll
            for (int i = 0; i < 16; ++i) accA[i] = __expf(accA[i] - mrun);
            #pragma unroll
            for (int i = 0; i < 8; ++i) {
                zt[i] = accA[i] + accA[i + 8];
                sq[i] = fmaf(accA[i] * accA[i], accU[i],
                             accA[i + 8] * accA[i + 8] * accU[i + 8]);
            }
            #pragma unroll
            for (int i = 0; i < 4; ++i) { zt[i] += zt[i + 4]; sq[i] += sq[i + 4]; }
            float Zt = (zt[0] + zt[1]) + (zt[2] + zt[3]);
            float St = (sq[0] + sq[1]) + (sq[2] + sq[3]);
            Zt += __shfl_xor(Zt, 32); St += __shfl_xor(St, 32);
            Zrun += Zt; S2run += St;

            // ---- phase 2: PV ----
            #pragma unroll
            for (int c2 = 0; c2 < 2; ++c2) {
                unsigned pE[4], pE2[4], pEU[4], pE3[4];
                #pragma unroll
                for (int k = 0; k < 4; ++k) {
                    const int i0 = 8*c2 + 2*k;
                    const float e0 = accA[i0], e1 = accA[i0+1];
                    const float q0 = e0*e0, q1 = e1*e1;
                    const float t0 = q0*accU[i0], t1 = q1*accU[i0+1];
                    pE [k] = pk(e0, e1);
                    pE2[k] = pk(q0, q1);
                    pEU[k] = pk(t0, t1);
                    pE3[k] = pk(t0*e0, t1*e1);
                }
                bf8 BE  = mkB(pE [0], pE [1], pE [2], pE [3], h);
                bf8 BE2 = mkB(pE2[0], pE2[1], pE2[2], pE2[3], h);
                bf8 BEU = mkB(pEU[0], pEU[1], pEU[2], pEU[3], h);
                bf8 BE3 = mkB(pE3[0], pE3[1], pE3[2], pE3[3], h);
                #pragma unroll
                for (int dt = 0; dt < 2; ++dt) {
                    const ushort_t* vp = sb + 3 * 2048 + (dt * 2 + c2) * 512 + lane * 8;
                    bf8 Am = *(const bf8*)(vp + 0 * 2048);
                    bf8 Aw = *(const bf8*)(vp + 1 * 2048);
                    bf8 Av = *(const bf8*)(vp + 2 * 2048);
                    aN1[dt]  = __builtin_amdgcn_mfma_f32_32x32x16_bf16(Am, BE,  aN1[dt],  0, 0, 0);
                    aN2w[dt] = __builtin_amdgcn_mfma_f32_32x32x16_bf16(Aw, BE2, aN2w[dt], 0, 0, 0);
                    aM2[dt]  = __builtin_amdgcn_mfma_f32_32x32x16_bf16(Aw, BEU, aM2[dt],  0, 0, 0);
                    aM2[dt]  = __builtin_amdgcn_mfma_f32_32x32x16_bf16(Av, BE2, aM2[dt],  0, 0, 0);
                    aN3[dt]  = __builtin_amdgcn_mfma_f32_32x32x16_bf16(Aw, BE3, aN3[dt],  0, 0, 0);
                }
            }
            __builtin_amdgcn_s_setprio(0);
        }
        __builtin_amdgcn_sched_barrier(0);
        __builtin_amdgcn_s_barrier();
    }

    // ---- epilogue ----
    const float rZ  = 1.f / Zrun;
    const float rZ2 = rZ * rZ;
    const float sS  = S2run * rZ2;

    #pragma unroll
    for (int dt = 0; dt < 2; ++dt)
        #pragma unroll
        for (int i = 0; i < 16; ++i) {
            const int col = 32*dt + (i & 3) + 8*(i >> 2) + 4*h;
            sm.ep[w*32 + lh][col] = aN1[dt][i] * rZ;
        }
    __syncthreads();
    {
        const int row = tid >> 1, half = (tid & 1) * 32;
        const size_t o = ((size_t)b * NS + rb*128 + row) * ND + head * NDH + half;
        #pragma unroll
        for (int q4 = 0; q4 < 32; q4 += 4) {
            float4 t = make_float4(sm.ep[row][half+q4], sm.ep[row][half+q4+1],
                                   sm.ep[row][half+q4+2], sm.ep[row][half+q4+3]);
            float4 xi = *(const float4*)(x + o + q4);
            *(float4*)(out0 + o + q4) = make_float4(t.x+xi.x, t.y+xi.y, t.z+xi.z, t.w+xi.w);
        }
    }
    __syncthreads();
    #pragma unroll
    for (int dt = 0; dt < 2; ++dt)
        #pragma unroll
        for (int i = 0; i < 16; ++i) {
            const int col = 32*dt + (i & 3) + 8*(i >> 2) + 4*h;
            sm.ep[w*32 + lh][col] = rZ2 * fmaf(sS, aN2w[dt][i], aM2[dt][i]) - 2.f*rZ2*rZ*aN3[dt][i];
        }
    __syncthreads();
    {
        const int row = tid >> 1, half = (tid & 1) * 32;
        const size_t o = ((size_t)b * NS + rb*128 + row) * ND + head * NDH + half;
        #pragma unroll
        for (int q4 = 0; q4 < 32; q4 += 4) {
            float4 t = make_float4(sm.ep[row][half+q4], sm.ep[row][half+q4+1],
                                   sm.ep[row][half+q4+2], sm.ep[row][half+q4+3]);
            *(float4*)(out1 + o + q4) = t;
        }
    }
}

extern "C" void kernel_launch(void* const* d_in, const int* in_sizes, int n_in,
                              void* d_out, int out_size, void* d_ws, size_t ws_size,
                              hipStream_t stream)
{
    (void)in_sizes; (void)n_in; (void)out_size; (void)ws_size;
    const float* x  = (const float*)d_in[0];
    const float* vx = (const float*)d_in[1];
    const float* K  = (const float*)d_in[2];
    const float* VK = (const float*)d_in[3];
    const float* Vv = (const float*)d_in[4];
    const float* VV = (const float*)d_in[5];
    const float* Wm = (const float*)d_in[6];
    const float* Wv = (const float*)d_in[7];

    float* out0 = (float*)d_out;
    float* out1 = out0 + (size_t)NB * NS * ND;

    ushort_t* kmF = (ushort_t*)d_ws;   // 6 consecutive planes: kmF,k2F,kvF,vmF,wF,vvF
    ushort_t* k2F = kmF + M4;
    ushort_t* kvF = k2F + M4;
    ushort_t* vmF = kvF + M4;
    ushort_t* wF  = vmF + M4;
    ushort_t* vvF = wF  + M4;
    ushort_t* fxF = vvF + M4;          // 3 consecutive planes: fxF,fvxF,fx2F
    ushort_t* fvxF= fxF + M4;
    ushort_t* fx2F= fvxF+ M4;
    ushort_t* fmF = fx2F+ M4;          // 3 consecutive planes: fmF,fw2F,fvF
    ushort_t* fw2F= fmF + M1;
    ushort_t* fvF = fw2F+ M1;

    prep_all<<<4608, 256, 0, stream>>>(x, vx, K, VK, Vv, VV, Wm, Wv,
                                       kmF, k2F, kvF, vmF, wF, vvF,
                                       fxF, fvxF, fx2F, fmF, fw2F, fvF);
    attn_fused<<<512, 256, 0, stream>>>(fxF, fmF, kmF, x, out0, out1);
}